// Round 2
// baseline (2097.678 us; speedup 1.0000x reference)
//
#include <hip/hip_runtime.h>
#include <cmath>

#define BB 32
#define SS 64
#define TT 16
#define UU 1024
#define EE 256
#define VV 20200
#define G3 3072
#define NBLK 256

// workspace layout (float offsets)
#define WS_XEMBT 0                          // XembT [S][E][B]
#define WS_HT    (WS_XEMBT + SS*EE*BB)      // hT: 2 ping-pong slots of [U][B]
#define WS_ENC   (WS_HT + 2*UU*BB)          // encoded [(b*S+s)][U]
#define WS_PRE   (WS_ENC + BB*SS*UU)        // pre_enc [(b*S+s)][U]
#define WS_Q     (WS_PRE + BB*SS*UU)        // q [b][U]
#define WS_ESC   (WS_Q + BB*UU)             // scores [b][S]
#define WS_XT    (WS_ESC + BB*SS)           // ctx transposed [U][B]
#define WS_HDT   (WS_XT + UU*BB)            // dec hidden transposed [U][B]
#define WS_HD    (WS_HDT + UU*BB)           // Hdec [(b*T+t)][U]
#define WS_DEMB  (WS_HD + BB*TT*UU)         // Demb [(t*B+b)][E]
#define WS_GXD   (WS_DEMB + BB*TT*EE)       // GXd  [(t*B+b)][3U]
#define WS_BAR   (WS_GXD + BB*TT*G3)        // 3 barrier sets x 1024 uints

#define ACC4(A, V, S) do { (A).x += (V).x * (S); (A).y += (V).y * (S); \
                           (A).z += (V).z * (S); (A).w += (V).w * (S); } while (0)
#define RED4(A, M) do { (A).x += __shfl_xor((A).x, M, 64); (A).y += __shfl_xor((A).y, M, 64); \
                        (A).z += __shfl_xor((A).z, M, 64); (A).w += __shfl_xor((A).w, M, 64); } while (0)

__device__ __forceinline__ float sigmoidf_(float x) {
    return 1.0f / (1.0f + expf(-x));
}

// write-through store to the coherence point (no dirty L2 line -> no wbl2 needed
// at the barrier). Readers refresh via one acquire-inv per barrier.
__device__ __forceinline__ void store_agent(float* p, float v) {
    __hip_atomic_store(p, v, __ATOMIC_RELAXED, __HIP_MEMORY_SCOPE_AGENT);
}
__device__ __forceinline__ void store_agent_u(unsigned* p, unsigned v) {
    __hip_atomic_store(p, v, __ATOMIC_RELAXED, __HIP_MEMORY_SCOPE_AGENT);
}
__device__ __forceinline__ unsigned load_agent_u(unsigned* p) {
    return __hip_atomic_load(p, __ATOMIC_RELAXED, __HIP_MEMORY_SCOPE_AGENT);
}

// Grid barrier v2: store-slot arrival (no RMW serialization), leader-poll with a
// 32-lane vector load + __all, monotonic generation values (no reset, no parity).
// Layout per set (1024 uints): slot[0..255] = per-block gen; gflag at 256+grp*32
// (8 flags, separate 128B lines); rel at 512+grp*32 (8 release lines, <=32 pollers).
// Chain: block stores slot -> group leader (bid%32==0) polls 32 slots -> gflag ->
// root (bid 0) polls 8 gflags -> stores 8 rel words -> blocks poll their rel line.
__device__ __forceinline__ void grid_barrier(unsigned* base, int bid, unsigned g) {
    __syncthreads();   // each wave drains its own vm ops before wave 0 arrives
    if (threadIdx.x < 64) {
        const int lane = threadIdx.x;
        const int grp = bid >> 5;
        const unsigned gv = g + 1u;
        if (lane == 0) {
            __builtin_amdgcn_s_waitcnt(0);   // prior agent stores completed at LLC
            store_agent_u(base + bid, gv);
        }
        if ((bid & 31) == 0) {
            // group leader: wait for my group's 32 slots (vector poll, no RMW)
            for (;;) {
                unsigned v = load_agent_u(base + grp * 32 + (lane & 31));
                if (__all((int)(v >= gv))) break;
                __builtin_amdgcn_s_sleep(2);
            }
            if (lane == 0) store_agent_u(base + 256 + grp * 32, gv);
            if (bid == 0) {
                for (;;) {
                    unsigned v = load_agent_u(base + 256 + (lane & 7) * 32);
                    if (__all((int)(v >= gv))) break;
                    __builtin_amdgcn_s_sleep(2);
                }
                if (lane < 8) store_agent_u(base + 512 + lane * 32, gv);
            }
        }
        if (bid != 0) {
            while (load_agent_u(base + 512 + grp * 32) < gv) {
                __builtin_amdgcn_s_sleep(2);
            }
        }
        __builtin_amdgcn_fence(__ATOMIC_ACQUIRE, "agent");   // one inv: see remote stores
    }
    __syncthreads();
}

// ---------------- prep: gathers + zero init ----------------
__global__ __launch_bounds__(256) void k_prep(const int* __restrict__ enc_in,
                                              const float* __restrict__ Ee,
                                              const int* __restrict__ teacher,
                                              const float* __restrict__ Ed,
                                              float* __restrict__ ws) {
    int gid = blockIdx.x * 256 + threadIdx.x;
    const int NE = SS * EE * BB;               // 524288
    const int NH = UU * BB;                    // 32768
    const int ND = BB * TT * EE;               // 131072
    if (gid < NE) {
        int b = gid & 31;
        int e = (gid >> 5) & 255;
        int s = gid >> 13;
        ws[WS_XEMBT + gid] = Ee[(size_t)enc_in[b * SS + s] * EE + e];
    } else if (gid < NE + NH) {
        ws[WS_HT + (gid - NE)] = 0.0f;         // h(-1) = 0 (slot 0)
    } else if (gid < NE + NH + ND) {
        int idx = gid - NE - NH;
        int e = idx & 255;
        int row = idx >> 8;                     // t*32 + b
        int t = row >> 5, b = row & 31;
        ws[WS_DEMB + idx] = Ed[(size_t)teacher[b * TT + t] * EE + e];
    } else if (gid < NE + NH + ND + 3072) {
        ((unsigned*)(ws + WS_BAR))[gid - NE - NH - ND] = 0u;
    }
}

// ---------------- encoder: 64 GRU steps, persistent grid ----------------
// Block owns 4 output columns (j = bid*4+c); K split across 8 waves. The reduce
// thread (tid<128) carries its own h(t) in a REGISTER across steps (it is the
// producer AND the consumer of hold) -- no post-barrier LLC load for the update.
__global__ __launch_bounds__(512, 2) void k_encoder(const float* __restrict__ Wh,
                                                    const float* __restrict__ Wx,
                                                    const float* __restrict__ b_in,
                                                    const float* __restrict__ b_rec,
                                                    float* __restrict__ ws) {
    float* XembT = ws + WS_XEMBT;
    float* hT = ws + WS_HT;
    float* enc = ws + WS_ENC;
    unsigned* bar = (unsigned*)(ws + WS_BAR);

    __shared__ float Whs[12288];   // [k][12] : (z c0..3)(r c0..3)(h c0..3)
    __shared__ float Wxs[3072];    // [k][12]
    __shared__ float scr[4096];    // [wv][set(4)][c(4)][b(32)]

    const int tid = threadIdx.x;
    const int bid = blockIdx.x;
    const int wv = tid >> 6;
    const int lane = tid & 63;
    const int kp = lane & 7;
    const int rg = lane >> 3;

    for (int k = tid; k < 1024; k += 512) {
        #pragma unroll
        for (int g = 0; g < 3; ++g)
            *(float4*)(Whs + k * 12 + g * 4) =
                *(const float4*)(Wh + (size_t)k * G3 + g * 1024 + bid * 4);
    }
    if (tid < 256) {
        int k = tid;
        #pragma unroll
        for (int g = 0; g < 3; ++g)
            *(float4*)(Wxs + k * 12 + g * 4) =
                *(const float4*)(Wx + (size_t)k * G3 + g * 1024 + bid * 4);
    }

    // reduce-thread constants: thread (c = tid>>5, b = tid&31) owns output (col j, batch b)
    float bz_s = 0.f, br_s = 0.f, bci_s = 0.f, bcr_s = 0.f;
    int rc_ = 0, rb_ = 0, rj_ = 0;
    if (tid < 128) {
        rc_ = tid >> 5; rb_ = tid & 31; rj_ = bid * 4 + rc_;
        bz_s = b_in[rj_] + b_rec[rj_];
        br_s = b_in[1024 + rj_] + b_rec[1024 + rj_];
        bci_s = b_in[2048 + rj_];
        bcr_s = b_rec[2048 + rj_];
    }
    __syncthreads();

    const int hk0 = wv * 128 + kp;   // this lane's h k-base (step 8)
    const int xk0 = wv * 32 + kp;    // this lane's x k-base (step 8)
    float hreg = 0.f;                // register-carried h(t) for this thread's (rj_, rb_)

    for (int t = 0; t < SS; ++t) {
        const float* hprev = hT + (t & 1) * (UU * BB);
        float* hnext = hT + ((t & 1) ^ 1) * (UU * BB);

        float4 az[4], ar[4], ah[4], ax[4];
        #pragma unroll
        for (int c = 0; c < 4; ++c) {
            az[c] = make_float4(0.f, 0.f, 0.f, 0.f);
            ar[c] = make_float4(0.f, 0.f, 0.f, 0.f);
            ah[c] = make_float4(0.f, 0.f, 0.f, 0.f);
            ax[c] = make_float4(0.f, 0.f, 0.f, 0.f);
        }

        // ---- h @ Wh : 16 k per lane, whole wave = contiguous 1KB per load step ----
        {
            const float* hp = hprev + hk0 * 32 + rg * 4;
            float4 hb[16];
            #pragma unroll
            for (int u = 0; u < 16; ++u) hb[u] = *(const float4*)(hp + u * 256);
            #pragma unroll
            for (int u = 0; u < 16; ++u) {
                const float* wp = Whs + (hk0 + 8 * u) * 12;
                float4 wz = *(const float4*)wp;
                float4 wr_ = *(const float4*)(wp + 4);
                float4 wc_ = *(const float4*)(wp + 8);
                float4 hv = hb[u];
                ACC4(az[0], hv, wz.x); ACC4(az[1], hv, wz.y); ACC4(az[2], hv, wz.z); ACC4(az[3], hv, wz.w);
                ACC4(ar[0], hv, wr_.x); ACC4(ar[1], hv, wr_.y); ACC4(ar[2], hv, wr_.z); ACC4(ar[3], hv, wr_.w);
                ACC4(ah[0], hv, wc_.x); ACC4(ah[1], hv, wc_.y); ACC4(ah[2], hv, wc_.z); ACC4(ah[3], hv, wc_.w);
            }
        }
        // ---- x @ Wx : 4 k per lane ----
        {
            const float* xp = XembT + t * (EE * BB) + xk0 * 32 + rg * 4;
            float4 xb[4];
            #pragma unroll
            for (int u = 0; u < 4; ++u) xb[u] = *(const float4*)(xp + u * 256);
            #pragma unroll
            for (int u = 0; u < 4; ++u) {
                const float* wp = Wxs + (xk0 + 8 * u) * 12;
                float4 wz = *(const float4*)wp;
                float4 wr_ = *(const float4*)(wp + 4);
                float4 wc_ = *(const float4*)(wp + 8);
                float4 xv = xb[u];
                ACC4(az[0], xv, wz.x); ACC4(az[1], xv, wz.y); ACC4(az[2], xv, wz.z); ACC4(az[3], xv, wz.w);
                ACC4(ar[0], xv, wr_.x); ACC4(ar[1], xv, wr_.y); ACC4(ar[2], xv, wr_.z); ACC4(ar[3], xv, wr_.w);
                ACC4(ax[0], xv, wz.x * 0.f + wc_.x); ACC4(ax[1], xv, wc_.y); ACC4(ax[2], xv, wc_.z); ACC4(ax[3], xv, wc_.w);
            }
        }
        // ---- in-wave split-K reduce over kp ----
        #pragma unroll
        for (int m = 1; m <= 4; m <<= 1) {
            #pragma unroll
            for (int c = 0; c < 4; ++c) { RED4(az[c], m); RED4(ar[c], m); RED4(ah[c], m); RED4(ax[c], m); }
        }
        // ---- cross-wave reduce via LDS scratch ----
        if (kp == 0) {
            float* sb = scr + wv * 512 + rg * 4;
            #pragma unroll
            for (int c = 0; c < 4; ++c) {
                *(float4*)(sb + c * 32) = az[c];
                *(float4*)(sb + 128 + c * 32) = ar[c];
                *(float4*)(sb + 256 + c * 32) = ah[c];
                *(float4*)(sb + 384 + c * 32) = ax[c];
            }
        }
        __syncthreads();
        if (tid < 128) {
            float saz = 0.f, sar = 0.f, sah = 0.f, sax = 0.f;
            #pragma unroll
            for (int w = 0; w < 8; ++w) {
                const float* sb = scr + w * 512 + rc_ * 32 + rb_;
                saz += sb[0]; sar += sb[128]; sah += sb[256]; sax += sb[384];
            }
            float z = sigmoidf_(saz + bz_s);
            float r = sigmoidf_(sar + br_s);
            float cc = tanhf(sax + bci_s + r * (sah + bcr_s));
            float hnew = z * hreg + (1.0f - z) * cc;
            hreg = hnew;
            store_agent(&hnext[rj_ * 32 + rb_], hnew);     // write-through: no wbl2 at barrier
            enc[((size_t)rb_ * SS + t) * UU + rj_] = hnew; // cross-kernel only: normal store
        }
        grid_barrier(bar, bid, (unsigned)t);
    }
}

// ---------------- generic fp32 GEMM: C[M,N] = A[M,K]@B[K,N] + bias (64x128 tile) ----------------
__global__ __launch_bounds__(256) void k_gemm(const float* __restrict__ A,
                                              const float* __restrict__ Bm,
                                              const float* __restrict__ bias,
                                              float* __restrict__ C,
                                              int M, int N, int K) {
    __shared__ float As[16][68];
    __shared__ float Bs[16][132];
    const int rb = blockIdx.x * 64;
    const int cb = blockIdx.y * 128;
    const int tid = threadIdx.x;
    const int cg = tid & 31;
    const int rg = tid >> 5;
    float acc[8][4] = {{0.f}};

    const int arow = tid >> 2, akq = (tid & 3) * 4;
    const int bkk = tid >> 4, bc8 = (tid & 15) * 8;
    const bool nfull = (cb + 128 <= N);

    for (int k0 = 0; k0 < K; k0 += 16) {
        {
            float4 a4 = *(const float4*)(A + (size_t)(rb + arow) * K + k0 + akq);
            As[akq + 0][arow] = a4.x; As[akq + 1][arow] = a4.y;
            As[akq + 2][arow] = a4.z; As[akq + 3][arow] = a4.w;
        }
        {
            int col = cb + bc8;
            const float* bp = Bm + (size_t)(k0 + bkk) * N + col;
            if (nfull) {
                float4 x0 = *(const float4*)bp;
                float4 x1 = *(const float4*)(bp + 4);
                Bs[bkk][bc8 + 0] = x0.x; Bs[bkk][bc8 + 1] = x0.y; Bs[bkk][bc8 + 2] = x0.z; Bs[bkk][bc8 + 3] = x0.w;
                Bs[bkk][bc8 + 4] = x1.x; Bs[bkk][bc8 + 5] = x1.y; Bs[bkk][bc8 + 6] = x1.z; Bs[bkk][bc8 + 7] = x1.w;
            } else {
                #pragma unroll
                for (int jj = 0; jj < 8; ++jj)
                    Bs[bkk][bc8 + jj] = (col + jj < N) ? bp[jj] : 0.0f;
            }
        }
        __syncthreads();
        #pragma unroll
        for (int kk = 0; kk < 16; ++kk) {
            float4 a0 = *(const float4*)&As[kk][rg * 8];
            float4 a1 = *(const float4*)&As[kk][rg * 8 + 4];
            float4 b0 = *(const float4*)&Bs[kk][cg * 4];
            float av[8] = {a0.x, a0.y, a0.z, a0.w, a1.x, a1.y, a1.z, a1.w};
            float bv[4] = {b0.x, b0.y, b0.z, b0.w};
            #pragma unroll
            for (int i = 0; i < 8; ++i)
                #pragma unroll
                for (int jj = 0; jj < 4; ++jj)
                    acc[i][jj] += av[i] * bv[jj];
        }
        __syncthreads();
    }
    const int col0 = cb + cg * 4;
    const bool cfull = (col0 + 4 <= N);
    #pragma unroll
    for (int i = 0; i < 8; ++i) {
        int row = rb + rg * 8 + i;
        float* cp = C + (size_t)row * N + col0;
        if (cfull) {
            float4 o;
            o.x = acc[i][0] + bias[col0 + 0];
            o.y = acc[i][1] + bias[col0 + 1];
            o.z = acc[i][2] + bias[col0 + 2];
            o.w = acc[i][3] + bias[col0 + 3];
            *(float4*)cp = o;
        } else {
            #pragma unroll
            for (int jj = 0; jj < 4; ++jj)
                if (col0 + jj < N) cp[jj] = acc[i][jj] + bias[col0 + jj];
        }
    }
}

// ---------------- 128x128-tile GEMM, 8x8 per thread (for the big logits GEMM) ----------------
// 1.0 FMA per LDS byte (vs 0.67 in k_gemm) -> not LDS-BW-bound. M must be /128, K /16.
__global__ __launch_bounds__(256) void k_gemm128(const float* __restrict__ A,
                                                 const float* __restrict__ Bm,
                                                 const float* __restrict__ bias,
                                                 float* __restrict__ C,
                                                 int M, int N, int K) {
    __shared__ float As[16][132];
    __shared__ float Bs[16][132];
    const int rb = blockIdx.x * 128;
    const int cb = blockIdx.y * 128;
    const int tid = threadIdx.x;
    const int rg = tid >> 4;      // 0..15
    const int cg = tid & 15;      // 0..15
    float acc[8][8] = {{0.f}};

    const int arow = tid >> 1, akq = (tid & 1) * 8;
    const int bkk = tid >> 4, bc8 = (tid & 15) * 8;
    const bool nfull = (cb + 128 <= N);

    for (int k0 = 0; k0 < K; k0 += 16) {
        {
            const float* ap = A + (size_t)(rb + arow) * K + k0 + akq;
            float4 a0 = *(const float4*)ap;
            float4 a1 = *(const float4*)(ap + 4);
            As[akq + 0][arow] = a0.x; As[akq + 1][arow] = a0.y;
            As[akq + 2][arow] = a0.z; As[akq + 3][arow] = a0.w;
            As[akq + 4][arow] = a1.x; As[akq + 5][arow] = a1.y;
            As[akq + 6][arow] = a1.z; As[akq + 7][arow] = a1.w;
        }
        {
            int col = cb + bc8;
            const float* bp = Bm + (size_t)(k0 + bkk) * N + col;
            if (nfull) {
                *(float4*)&Bs[bkk][bc8] = *(const float4*)bp;
                *(float4*)&Bs[bkk][bc8 + 4] = *(const float4*)(bp + 4);
            } else {
                #pragma unroll
                for (int jj = 0; jj < 8; ++jj)
                    Bs[bkk][bc8 + jj] = (col + jj < N) ? bp[jj] : 0.0f;
            }
        }
        __syncthreads();
        #pragma unroll
        for (int kk = 0; kk < 16; ++kk) {
            float4 a0 = *(const float4*)&As[kk][rg * 8];
            float4 a1 = *(const float4*)&As[kk][rg * 8 + 4];
            float4 b0 = *(const float4*)&Bs[kk][cg * 8];
            float4 b1 = *(const float4*)&Bs[kk][cg * 8 + 4];
            float av[8] = {a0.x, a0.y, a0.z, a0.w, a1.x, a1.y, a1.z, a1.w};
            float bw[8] = {b0.x, b0.y, b0.z, b0.w, b1.x, b1.y, b1.z, b1.w};
            #pragma unroll
            for (int i = 0; i < 8; ++i)
                #pragma unroll
                for (int jj = 0; jj < 8; ++jj)
                    acc[i][jj] += av[i] * bw[jj];
        }
        __syncthreads();
    }
    const int col0 = cb + cg * 8;
    const bool cfull = (col0 + 8 <= N);
    #pragma unroll
    for (int i = 0; i < 8; ++i) {
        int row = rb + rg * 8 + i;
        float* cp = C + (size_t)row * N + col0;
        if (cfull) {
            float4 o0, o1;
            o0.x = acc[i][0] + bias[col0 + 0];
            o0.y = acc[i][1] + bias[col0 + 1];
            o0.z = acc[i][2] + bias[col0 + 2];
            o0.w = acc[i][3] + bias[col0 + 3];
            o1.x = acc[i][4] + bias[col0 + 4];
            o1.y = acc[i][5] + bias[col0 + 5];
            o1.z = acc[i][6] + bias[col0 + 6];
            o1.w = acc[i][7] + bias[col0 + 7];
            *(float4*)cp = o0;
            *(float4*)(cp + 4) = o1;
        } else {
            #pragma unroll
            for (int jj = 0; jj < 8; ++jj)
                if (col0 + jj < N) cp[jj] = acc[i][jj] + bias[col0 + jj];
        }
    }
}

// ---------------- decoder: 16 steps x 4 phases, persistent grid ----------------
__global__ __launch_bounds__(256, 1) void k_decoder(const float* __restrict__ W2,
                                                    const float* __restrict__ b2,
                                                    const float* __restrict__ Va,
                                                    const float* __restrict__ bv,
                                                    const float* __restrict__ Wxd,
                                                    const float* __restrict__ b_rec,
                                                    float* __restrict__ ws) {
    float* hT = ws + WS_HT;            // slot 0 = encoder final hidden
    float* enc = ws + WS_ENC;
    float* pre = ws + WS_PRE;
    float* q = ws + WS_Q;
    float* esc = ws + WS_ESC;
    float* xT = ws + WS_XT;
    float* hdT = ws + WS_HDT;
    float* Hd = ws + WS_HD;
    float* GXd = ws + WS_GXD;
    unsigned* bar = (unsigned*)(ws + WS_BAR) + 1024;

    __shared__ float Wxds[12288];      // [k][12] g-major
    __shared__ float W2s[4096];        // [k][4] cols bid*4..+3
    __shared__ float scr[1536];        // [wv][set(3)][c(4)][b(32)]
    __shared__ float eL[64];
    __shared__ float attnL[64];
    __shared__ float shs[256];

    const int tid = threadIdx.x;
    const int bid = blockIdx.x;
    const int wv = tid >> 6;
    const int lane = tid & 63;
    const int kp = lane & 7;
    const int rg = lane >> 3;

    for (int k = tid; k < 1024; k += 256) {
        #pragma unroll
        for (int g = 0; g < 3; ++g)
            *(float4*)(Wxds + k * 12 + g * 4) =
                *(const float4*)(Wxd + (size_t)k * G3 + g * 1024 + bid * 4);
        *(float4*)(W2s + k * 4) = *(const float4*)(W2 + (size_t)k * UU + bid * 4);
    }

    float bzr_s = 0.f, brr_s = 0.f, bcr_s = 0.f;
    int rc_ = 0, rb_ = 0, rj_ = 0;
    if (tid < 128) {
        rc_ = tid >> 5; rb_ = tid & 31; rj_ = bid * 4 + rc_;
        bzr_s = b_rec[rj_];
        brr_s = b_rec[1024 + rj_];
        bcr_s = b_rec[2048 + rj_];
    }
    __syncthreads();

    const int xk0 = wv * 256 + kp;     // S4 k-base for this lane
    unsigned bc = 0;

    for (int t = 0; t < TT; ++t) {
        const float* hsrc = (t == 0) ? hT : hdT;

        // prefetch this step's GXd gate values early: overlaps S1..S3 + 3 barriers
        float gxz = 0.f, gxr = 0.f, gxc = 0.f;
        if (tid < 128) {
            const float* gx = GXd + (size_t)(t * BB + rb_) * G3;
            gxz = gx[rj_];
            gxr = gx[1024 + rj_];
            gxc = gx[2048 + rj_];
        }

        // ---- S1: q = dec_h @ W2 + b2 (4 q-cols per block, W2 from LDS) ----
        {
            const int cq = lane & 3;
            const int kpq = (lane >> 2) & 7;
            const int rgq = (lane >> 5) | (wv << 1);
            const int qc = bid * 4 + cq;
            const float* hp = hsrc + kpq * 32 + rgq * 4;
            float a0 = 0, a1 = 0, a2 = 0, a3 = 0;
            for (int g = 0; g < 16; ++g) {
                float4 hv[8]; float wr[8];
                #pragma unroll
                for (int u = 0; u < 8; ++u) {
                    hv[u] = *(const float4*)(hp + (g * 8 + u) * 256);
                    wr[u] = W2s[(kpq + 8 * (g * 8 + u)) * 4 + cq];
                }
                #pragma unroll
                for (int u = 0; u < 8; ++u) {
                    a0 += hv[u].x * wr[u]; a1 += hv[u].y * wr[u];
                    a2 += hv[u].z * wr[u]; a3 += hv[u].w * wr[u];
                }
            }
            #pragma unroll
            for (int m = 4; m <= 16; m <<= 1) {
                a0 += __shfl_xor(a0, m, 64); a1 += __shfl_xor(a1, m, 64);
                a2 += __shfl_xor(a2, m, 64); a3 += __shfl_xor(a3, m, 64);
            }
            if (kpq == 0) {
                float bb2 = b2[qc];
                store_agent(&q[(size_t)(rgq * 4 + 0) * UU + qc], a0 + bb2);
                store_agent(&q[(size_t)(rgq * 4 + 1) * UU + qc], a1 + bb2);
                store_agent(&q[(size_t)(rgq * 4 + 2) * UU + qc], a2 + bb2);
                store_agent(&q[(size_t)(rgq * 4 + 3) * UU + qc], a3 + bb2);
            }
        }
        grid_barrier(bar, bid, bc++);

        // ---- S2: scores e[b][s] = tanh(pre_enc + q) . Va + bv ----
        {
            const int b = bid >> 3, s0 = (bid & 7) * 8;
            const int pi = tid >> 5, kq = tid & 31;
            const int srow = s0 + pi;
            const float* pe = pre + ((size_t)b * SS + srow) * UU;
            const float* qb = q + (size_t)b * UU;
            float acc = 0;
            #pragma unroll
            for (int kk = 0; kk < 8; ++kk) {
                int k = kq * 32 + kk * 4;
                float4 p4 = *(const float4*)(pe + k);
                float4 q4 = *(const float4*)(qb + k);
                float4 v4 = *(const float4*)(Va + k);
                acc += tanhf(p4.x + q4.x) * v4.x + tanhf(p4.y + q4.y) * v4.y +
                       tanhf(p4.z + q4.z) * v4.z + tanhf(p4.w + q4.w) * v4.w;
            }
            #pragma unroll
            for (int m = 16; m >= 1; m >>= 1) acc += __shfl_xor(acc, m, 32);
            if (kq == 0) store_agent(&esc[b * SS + srow], acc + bv[0]);
        }
        grid_barrier(bar, bid, bc++);

        // ---- S3: softmax + ctx (coalesced over U) into xT ----
        {
            const int b = bid >> 3, ug = bid & 7;
            if (tid < 64) eL[tid] = esc[b * SS + tid];
            __syncthreads();
            if (tid < 64) {
                float v = eL[tid];
                float m = v;
                #pragma unroll
                for (int mm = 32; mm >= 1; mm >>= 1) m = fmaxf(m, __shfl_xor(m, mm, 64));
                float p = expf(v - m);
                float sum = p;
                #pragma unroll
                for (int mm = 32; mm >= 1; mm >>= 1) sum += __shfl_xor(sum, mm, 64);
                attnL[tid] = p / sum;
            }
            __syncthreads();
            const int u = ug * 128 + (tid & 127), sp = tid >> 7;
            float acc = 0;
            #pragma unroll 8
            for (int i = 0; i < 32; ++i) {
                int srow = sp * 32 + i;
                acc += attnL[srow] * enc[((size_t)b * SS + srow) * UU + u];
            }
            shs[(tid & 127) * 2 + sp] = acc;
            __syncthreads();
            if (tid < 128)
                store_agent(&xT[(size_t)(ug * 128 + tid) * BB + b], shs[tid * 2] + shs[tid * 2 + 1]);
        }
        grid_barrier(bar, bid, bc++);

        // ---- S4: gx = ctx @ Wxd_top (+ GXd), k-split across 4 waves ----
        {
            float4 sz[4], sr_[4], sc_[4];
            #pragma unroll
            for (int c = 0; c < 4; ++c) {
                sz[c] = make_float4(0.f, 0.f, 0.f, 0.f);
                sr_[c] = make_float4(0.f, 0.f, 0.f, 0.f);
                sc_[c] = make_float4(0.f, 0.f, 0.f, 0.f);
            }
            const float* xp = xT + xk0 * 32 + rg * 4;
            #pragma unroll
            for (int gg = 0; gg < 2; ++gg) {
                float4 xb[16];
                #pragma unroll
                for (int u = 0; u < 16; ++u) xb[u] = *(const float4*)(xp + (gg * 16 + u) * 256);
                #pragma unroll
                for (int u = 0; u < 16; ++u) {
                    const float* wp = Wxds + (xk0 + 8 * (gg * 16 + u)) * 12;
                    float4 wz = *(const float4*)wp;
                    float4 wr4 = *(const float4*)(wp + 4);
                    float4 wc4 = *(const float4*)(wp + 8);
                    float4 xv = xb[u];
                    ACC4(sz[0], xv, wz.x); ACC4(sz[1], xv, wz.y); ACC4(sz[2], xv, wz.z); ACC4(sz[3], xv, wz.w);
                    ACC4(sr_[0], xv, wr4.x); ACC4(sr_[1], xv, wr4.y); ACC4(sr_[2], xv, wr4.z); ACC4(sr_[3], xv, wr4.w);
                    ACC4(sc_[0], xv, wc4.x); ACC4(sc_[1], xv, wc4.y); ACC4(sc_[2], xv, wc4.z); ACC4(sc_[3], xv, wc4.w);
                }
            }
            #pragma unroll
            for (int m = 1; m <= 4; m <<= 1) {
                #pragma unroll
                for (int c = 0; c < 4; ++c) { RED4(sz[c], m); RED4(sr_[c], m); RED4(sc_[c], m); }
            }
            if (kp == 0) {
                float* sb = scr + wv * 384 + rg * 4;
                #pragma unroll
                for (int c = 0; c < 4; ++c) {
                    *(float4*)(sb + c * 32) = sz[c];
                    *(float4*)(sb + 128 + c * 32) = sr_[c];
                    *(float4*)(sb + 256 + c * 32) = sc_[c];
                }
            }
            __syncthreads();
            if (tid < 128) {
                float ssz = 0.f, ssr = 0.f, ssc = 0.f;
                #pragma unroll
                for (int w = 0; w < 4; ++w) {
                    const float* sb = scr + w * 384 + rc_ * 32 + rb_;
                    ssz += sb[0]; ssr += sb[128]; ssc += sb[256];
                }
                float z = sigmoidf_(ssz + gxz + bzr_s);
                float rr = sigmoidf_(ssr + gxr + brr_s);
                float cc = tanhf(ssc + gxc + rr * bcr_s);
                float h = (1.0f - z) * cc;       // z*h0 + (1-z)*c, h0 = 0
                Hd[((size_t)rb_ * TT + t) * UU + rj_] = h;   // cross-kernel: normal
                store_agent(&hdT[(size_t)rj_ * BB + rb_], h);
            }
        }
        grid_barrier(bar, bid, bc++);
    }
}

// ---------------- argmax with numpy first-index tie-break ----------------
__global__ __launch_bounds__(256) void k_argmax(const float* __restrict__ logits,
                                                float* __restrict__ outp) {
    const int row = blockIdx.x;
    const float* lr = logits + (size_t)row * VV;
    const int tid = threadIdx.x;
    float best = -INFINITY;
    int bidx = 0x7fffffff;
    for (int c = tid; c < VV; c += 256) {
        float v = lr[c];
        if (v > best) { best = v; bidx = c; }
    }
    __shared__ float bv_[256];
    __shared__ int bi_[256];
    bv_[tid] = best; bi_[tid] = bidx;
    __syncthreads();
    for (int s2 = 128; s2 > 0; s2 >>= 1) {
        if (tid < s2) {
            float ov = bv_[tid + s2]; int oi = bi_[tid + s2];
            if (ov > bv_[tid] || (ov == bv_[tid] && oi < bi_[tid])) {
                bv_[tid] = ov; bi_[tid] = oi;
            }
        }
        __syncthreads();
    }
    if (tid == 0) outp[row] = (float)bi_[0];
}

extern "C" void kernel_launch(void* const* d_in, const int* in_sizes, int n_in,
                              void* d_out, int out_size, void* d_ws, size_t ws_size,
                              hipStream_t stream) {
    const int* enc_in = (const int*)d_in[0];
    const int* teacher = (const int*)d_in[1];
    const float* Ee = (const float*)d_in[4];
    const float* eWx = (const float*)d_in[5];
    const float* eWh = (const float*)d_in[6];
    const float* eb_in = (const float*)d_in[7];
    const float* eb_rec = (const float*)d_in[8];
    const float* Ed = (const float*)d_in[9];
    const float* dWx = (const float*)d_in[10];
    // d_in[11] dec_Wh structurally unused: h0_dec == 0 -> gh == b_rec
    const float* db_in = (const float*)d_in[12];
    const float* db_rec = (const float*)d_in[13];
    const float* W1 = (const float*)d_in[14];
    const float* b1 = (const float*)d_in[15];
    const float* W2 = (const float*)d_in[16];
    const float* b2 = (const float*)d_in[17];
    const float* Va = (const float*)d_in[18];
    const float* bvv = (const float*)d_in[19];
    const float* Wf = (const float*)d_in[20];
    const float* bf = (const float*)d_in[21];
    float* ws = (float*)d_ws;
    float* out = (float*)d_out;

    // prep: XembT gather + hT slot0 zero + Demb gather + barrier zero (3 sets)
    const int NTOT = SS * EE * BB + UU * BB + BB * TT * EE + 3072;
    k_prep<<<dim3((NTOT + 255) / 256), dim3(256), 0, stream>>>(enc_in, Ee, teacher, Ed, ws);

    // GXd = Demb @ dec_Wx[1024:1280,:] + dec_b_in : [512,256]x[256,3072]
    k_gemm<<<dim3(8, 24), dim3(256), 0, stream>>>(ws + WS_DEMB, dWx + (size_t)UU * G3, db_in,
                                                  ws + WS_GXD, BB * TT, G3, EE);

    // encoder recurrence (persistent, 64 steps, 512 threads/block)
    k_encoder<<<dim3(NBLK), dim3(512), 0, stream>>>(eWh, eWx, eb_in, eb_rec, ws);

    // pre_enc = encoded @ W1 + b1 : [2048,1024]x[1024,1024]
    k_gemm<<<dim3(32, 8), dim3(256), 0, stream>>>(ws + WS_ENC, W1, b1, ws + WS_PRE, BB * SS, UU, UU);

    // decoder (persistent, 16 steps x 4 phases)
    k_decoder<<<dim3(NBLK), dim3(256), 0, stream>>>(W2, b2, Va, bvv, dWx, db_rec, ws);

    // logits = Hdec @ Wf + bf : [512,1024]x[1024,20200] -> d_out (128x128 tile)
    k_gemm128<<<dim3(4, 158), dim3(256), 0, stream>>>(ws + WS_HD, Wf, bf, out, BB * TT, VV, UU);

    // predictions = argmax(logits)
    k_argmax<<<dim3(BB * TT), dim3(256), 0, stream>>>(out, out + (size_t)BB * TT * VV);
}

// Round 3
// 1918.986 us; speedup vs baseline: 1.0931x; 1.0931x over previous
//
#include <hip/hip_runtime.h>
#include <cmath>

#define BB 32
#define SS 64
#define TT 16
#define UU 1024
#define EE 256
#define VV 20200
#define G3 3072
#define NBLK 256

// workspace layout (float offsets)
#define WS_XEMBT 0                          // XembT [S][E][B]
#define WS_HT    (WS_XEMBT + SS*EE*BB)      // hT: 2 ping-pong slots of [U][B]
#define WS_ENC   (WS_HT + 2*UU*BB)          // encoded [(b*S+s)][U]
#define WS_PRE   (WS_ENC + BB*SS*UU)        // pre_enc [(b*S+s)][U]
#define WS_Q     (WS_PRE + BB*SS*UU)        // q [b][U]
#define WS_ESC   (WS_Q + BB*UU)             // scores [b][S]
#define WS_XT    (WS_ESC + BB*SS)           // ctx transposed [U][B]
#define WS_HDT   (WS_XT + UU*BB)            // dec hidden transposed [U][B]
#define WS_HD    (WS_HDT + UU*BB)           // Hdec [(b*T+t)][U]
#define WS_DEMB  (WS_HD + BB*TT*UU)         // Demb [(t*B+b)][E]
#define WS_GXD   (WS_DEMB + BB*TT*EE)       // GXd  [(t*B+b)][3U]
#define WS_BAR   (WS_GXD + BB*TT*G3)        // 3 barrier sets x 1024 uints

#define ACC4(A, V, S) do { (A).x += (V).x * (S); (A).y += (V).y * (S); \
                           (A).z += (V).z * (S); (A).w += (V).w * (S); } while (0)
#define RED4(A, M) do { (A).x += __shfl_xor((A).x, M, 64); (A).y += __shfl_xor((A).y, M, 64); \
                        (A).z += __shfl_xor((A).z, M, 64); (A).w += __shfl_xor((A).w, M, 64); } while (0)

typedef float f4v __attribute__((ext_vector_type(4)));

__device__ __forceinline__ float sigmoidf_(float x) {
    return 1.0f / (1.0f + expf(-x));
}

// write-through store to the coherence point (LLC). Paired with sc0/sc1 bypass
// loads on the consumer side -> NO acquire-inv needed anywhere in the hot loops.
__device__ __forceinline__ void store_agent(float* p, float v) {
    __hip_atomic_store(p, v, __ATOMIC_RELAXED, __HIP_MEMORY_SCOPE_AGENT);
}
__device__ __forceinline__ void store_agent_u(unsigned* p, unsigned v) {
    __hip_atomic_store(p, v, __ATOMIC_RELAXED, __HIP_MEMORY_SCOPE_AGENT);
}
__device__ __forceinline__ unsigned load_agent_u(unsigned* p) {
    return __hip_atomic_load(p, __ATOMIC_RELAXED, __HIP_MEMORY_SCOPE_AGENT);
}

// 16 device-coherent (L1/L2-bypass) float4 loads at stride 256 floats (1024 B),
// 4 base addresses + imm offsets, ONE trailing waitcnt -> 16-deep MLP per lane.
__device__ __forceinline__ void llc_load16(const float* p, f4v* o) {
    asm volatile(
        "global_load_dwordx4 %0, %16, off sc0 sc1\n\t"
        "global_load_dwordx4 %1, %16, off offset:1024 sc0 sc1\n\t"
        "global_load_dwordx4 %2, %16, off offset:2048 sc0 sc1\n\t"
        "global_load_dwordx4 %3, %16, off offset:3072 sc0 sc1\n\t"
        "global_load_dwordx4 %4, %17, off sc0 sc1\n\t"
        "global_load_dwordx4 %5, %17, off offset:1024 sc0 sc1\n\t"
        "global_load_dwordx4 %6, %17, off offset:2048 sc0 sc1\n\t"
        "global_load_dwordx4 %7, %17, off offset:3072 sc0 sc1\n\t"
        "global_load_dwordx4 %8, %18, off sc0 sc1\n\t"
        "global_load_dwordx4 %9, %18, off offset:1024 sc0 sc1\n\t"
        "global_load_dwordx4 %10, %18, off offset:2048 sc0 sc1\n\t"
        "global_load_dwordx4 %11, %18, off offset:3072 sc0 sc1\n\t"
        "global_load_dwordx4 %12, %19, off sc0 sc1\n\t"
        "global_load_dwordx4 %13, %19, off offset:1024 sc0 sc1\n\t"
        "global_load_dwordx4 %14, %19, off offset:2048 sc0 sc1\n\t"
        "global_load_dwordx4 %15, %19, off offset:3072 sc0 sc1\n\t"
        "s_waitcnt vmcnt(0)"
        : "=&v"(o[0]), "=&v"(o[1]), "=&v"(o[2]), "=&v"(o[3]),
          "=&v"(o[4]), "=&v"(o[5]), "=&v"(o[6]), "=&v"(o[7]),
          "=&v"(o[8]), "=&v"(o[9]), "=&v"(o[10]), "=&v"(o[11]),
          "=&v"(o[12]), "=&v"(o[13]), "=&v"(o[14]), "=&v"(o[15])
        : "v"(p), "v"(p + 1024), "v"(p + 2048), "v"(p + 3072)
        : "memory");
}

// 4 contiguous float4 bypass loads (64 B per lane)
__device__ __forceinline__ void llc_load4(const float* p, f4v* o) {
    asm volatile(
        "global_load_dwordx4 %0, %4, off sc0 sc1\n\t"
        "global_load_dwordx4 %1, %4, off offset:16 sc0 sc1\n\t"
        "global_load_dwordx4 %2, %4, off offset:32 sc0 sc1\n\t"
        "global_load_dwordx4 %3, %4, off offset:48 sc0 sc1\n\t"
        "s_waitcnt vmcnt(0)"
        : "=&v"(o[0]), "=&v"(o[1]), "=&v"(o[2]), "=&v"(o[3])
        : "v"(p) : "memory");
}

__device__ __forceinline__ float llc_loadf(const float* p) {
    float r;
    asm volatile("global_load_dword %0, %1, off sc0 sc1\n\ts_waitcnt vmcnt(0)"
                 : "=&v"(r) : "v"(p) : "memory");
    return r;
}

// Grid barrier v3: store-slot arrival + leader poll, NO acquire fence.
// Visibility contract: producers use write-through agent stores, drained by the
// per-wave vmcnt(0) that __syncthreads emits (+ explicit waitcnt on wave 0)
// BEFORE the flag store; consumers read shared data with sc0/sc1 bypass loads
// issued only after observing the release flag. Read-only arrays stay L2-hot.
__device__ __forceinline__ void grid_barrier(unsigned* base, int bid, unsigned g) {
    __syncthreads();   // each wave drains its own vmem (incl. agent stores)
    if (threadIdx.x < 64) {
        const int lane = threadIdx.x;
        const int grp = bid >> 5;
        const unsigned gv = g + 1u;
        if (lane == 0) {
            asm volatile("" ::: "memory");
            __builtin_amdgcn_s_waitcnt(0);
            store_agent_u(base + bid, gv);
        }
        if ((bid & 31) == 0) {
            for (;;) {
                unsigned v = load_agent_u(base + grp * 32 + (lane & 31));
                if (__all((int)(v >= gv))) break;
                __builtin_amdgcn_s_sleep(2);
            }
            if (lane == 0) store_agent_u(base + 256 + grp * 32, gv);
            if (bid == 0) {
                for (;;) {
                    unsigned v = load_agent_u(base + 256 + (lane & 7) * 32);
                    if (__all((int)(v >= gv))) break;
                    __builtin_amdgcn_s_sleep(2);
                }
                if (lane < 8) store_agent_u(base + 512 + lane * 32, gv);
            }
        }
        if (bid != 0) {
            while (load_agent_u(base + 512 + grp * 32) < gv) {
                __builtin_amdgcn_s_sleep(2);
            }
        }
    }
    __syncthreads();
}

// ---------------- prep: gathers + zero init ----------------
__global__ __launch_bounds__(256) void k_prep(const int* __restrict__ enc_in,
                                              const float* __restrict__ Ee,
                                              const int* __restrict__ teacher,
                                              const float* __restrict__ Ed,
                                              float* __restrict__ ws) {
    int gid = blockIdx.x * 256 + threadIdx.x;
    const int NE = SS * EE * BB;               // 524288
    const int NH = UU * BB;                    // 32768
    const int ND = BB * TT * EE;               // 131072
    if (gid < NE) {
        int b = gid & 31;
        int e = (gid >> 5) & 255;
        int s = gid >> 13;
        ws[WS_XEMBT + gid] = Ee[(size_t)enc_in[b * SS + s] * EE + e];
    } else if (gid < NE + NH) {
        ws[WS_HT + (gid - NE)] = 0.0f;         // h(-1) = 0 (slot 0)
    } else if (gid < NE + NH + ND) {
        int idx = gid - NE - NH;
        int e = idx & 255;
        int row = idx >> 8;                     // t*32 + b
        int t = row >> 5, b = row & 31;
        ws[WS_DEMB + idx] = Ed[(size_t)teacher[b * TT + t] * EE + e];
    } else if (gid < NE + NH + ND + 3072) {
        ((unsigned*)(ws + WS_BAR))[gid - NE - NH - ND] = 0u;
    }
}

// ---------------- encoder: 64 GRU steps, persistent grid ----------------
// Block owns 4 output cols; K split across 8 waves (16 k per lane). h is read
// via sc0/sc1 LLC-bypass loads (no acquire-inv in the loop!), so XembT and
// everything read-only stays L2-resident across all 64 steps.
__global__ __launch_bounds__(512, 2) void k_encoder(const float* __restrict__ Wh,
                                                    const float* __restrict__ Wx,
                                                    const float* __restrict__ b_in,
                                                    const float* __restrict__ b_rec,
                                                    float* __restrict__ ws) {
    float* XembT = ws + WS_XEMBT;
    float* hT = ws + WS_HT;
    float* enc = ws + WS_ENC;
    unsigned* bar = (unsigned*)(ws + WS_BAR);

    __shared__ float Whs[12288];   // [k][12] : (z c0..3)(r c0..3)(h c0..3)
    __shared__ float Wxs[3072];    // [k][12]
    __shared__ float scr[4096];    // [wv][set(4)][c(4)][b(32)]

    const int tid = threadIdx.x;
    const int bid = blockIdx.x;
    const int wv = tid >> 6;
    const int lane = tid & 63;
    const int kp = lane & 7;
    const int rg = lane >> 3;

    for (int k = tid; k < 1024; k += 512) {
        #pragma unroll
        for (int g = 0; g < 3; ++g)
            *(float4*)(Whs + k * 12 + g * 4) =
                *(const float4*)(Wh + (size_t)k * G3 + g * 1024 + bid * 4);
    }
    if (tid < 256) {
        int k = tid;
        #pragma unroll
        for (int g = 0; g < 3; ++g)
            *(float4*)(Wxs + k * 12 + g * 4) =
                *(const float4*)(Wx + (size_t)k * G3 + g * 1024 + bid * 4);
    }

    float bz_s = 0.f, br_s = 0.f, bci_s = 0.f, bcr_s = 0.f;
    int rc_ = 0, rb_ = 0, rj_ = 0;
    if (tid < 128) {
        rc_ = tid >> 5; rb_ = tid & 31; rj_ = bid * 4 + rc_;
        bz_s = b_in[rj_] + b_rec[rj_];
        br_s = b_in[1024 + rj_] + b_rec[1024 + rj_];
        bci_s = b_in[2048 + rj_];
        bcr_s = b_rec[2048 + rj_];
    }
    __syncthreads();

    const int hk0 = wv * 128 + kp;   // this lane's h k-base (step 8)
    const int xk0 = wv * 32 + kp;    // this lane's x k-base (step 8)
    float hreg = 0.f;                // register-carried h(t) for (rj_, rb_)

    for (int t = 0; t < SS; ++t) {
        const float* hprev = hT + (t & 1) * (UU * BB);
        float* hnext = hT + ((t & 1) ^ 1) * (UU * BB);

        float4 az[4], ar[4], ah[4], ax[4];
        #pragma unroll
        for (int c = 0; c < 4; ++c) {
            az[c] = make_float4(0.f, 0.f, 0.f, 0.f);
            ar[c] = make_float4(0.f, 0.f, 0.f, 0.f);
            ah[c] = make_float4(0.f, 0.f, 0.f, 0.f);
            ax[c] = make_float4(0.f, 0.f, 0.f, 0.f);
        }

        // ---- x @ Wx first (plain loads, L2-hot after step 0) ----
        {
            const float* xp = XembT + t * (EE * BB) + xk0 * 32 + rg * 4;
            float4 xb[4];
            #pragma unroll
            for (int u = 0; u < 4; ++u) xb[u] = *(const float4*)(xp + u * 256);
            #pragma unroll
            for (int u = 0; u < 4; ++u) {
                const float* wp = Wxs + (xk0 + 8 * u) * 12;
                float4 wz = *(const float4*)wp;
                float4 wr_ = *(const float4*)(wp + 4);
                float4 wc_ = *(const float4*)(wp + 8);
                float4 xv = xb[u];
                ACC4(az[0], xv, wz.x); ACC4(az[1], xv, wz.y); ACC4(az[2], xv, wz.z); ACC4(az[3], xv, wz.w);
                ACC4(ar[0], xv, wr_.x); ACC4(ar[1], xv, wr_.y); ACC4(ar[2], xv, wr_.z); ACC4(ar[3], xv, wr_.w);
                ACC4(ax[0], xv, wc_.x); ACC4(ax[1], xv, wc_.y); ACC4(ax[2], xv, wc_.z); ACC4(ax[3], xv, wc_.w);
            }
        }
        // ---- h @ Wh : 16 k per lane via LLC-bypass burst ----
        {
            f4v hb[16];
            llc_load16(hprev + hk0 * 32 + rg * 4, hb);
            #pragma unroll
            for (int u = 0; u < 16; ++u) {
                const float* wp = Whs + (hk0 + 8 * u) * 12;
                float4 wz = *(const float4*)wp;
                float4 wr_ = *(const float4*)(wp + 4);
                float4 wc_ = *(const float4*)(wp + 8);
                f4v hv = hb[u];
                ACC4(az[0], hv, wz.x); ACC4(az[1], hv, wz.y); ACC4(az[2], hv, wz.z); ACC4(az[3], hv, wz.w);
                ACC4(ar[0], hv, wr_.x); ACC4(ar[1], hv, wr_.y); ACC4(ar[2], hv, wr_.z); ACC4(ar[3], hv, wr_.w);
                ACC4(ah[0], hv, wc_.x); ACC4(ah[1], hv, wc_.y); ACC4(ah[2], hv, wc_.z); ACC4(ah[3], hv, wc_.w);
            }
        }
        // ---- in-wave split-K reduce over kp ----
        #pragma unroll
        for (int m = 1; m <= 4; m <<= 1) {
            #pragma unroll
            for (int c = 0; c < 4; ++c) { RED4(az[c], m); RED4(ar[c], m); RED4(ah[c], m); RED4(ax[c], m); }
        }
        // ---- cross-wave reduce via LDS scratch ----
        if (kp == 0) {
            float* sb = scr + wv * 512 + rg * 4;
            #pragma unroll
            for (int c = 0; c < 4; ++c) {
                *(float4*)(sb + c * 32) = az[c];
                *(float4*)(sb + 128 + c * 32) = ar[c];
                *(float4*)(sb + 256 + c * 32) = ah[c];
                *(float4*)(sb + 384 + c * 32) = ax[c];
            }
        }
        __syncthreads();
        if (tid < 128) {
            float saz = 0.f, sar = 0.f, sah = 0.f, sax = 0.f;
            #pragma unroll
            for (int w = 0; w < 8; ++w) {
                const float* sb = scr + w * 512 + rc_ * 32 + rb_;
                saz += sb[0]; sar += sb[128]; sah += sb[256]; sax += sb[384];
            }
            float z = sigmoidf_(saz + bz_s);
            float r = sigmoidf_(sar + br_s);
            float cc = tanhf(sax + bci_s + r * (sah + bcr_s));
            float hnew = z * hreg + (1.0f - z) * cc;
            hreg = hnew;
            store_agent(&hnext[rj_ * 32 + rb_], hnew);     // write-through to LLC
            enc[((size_t)rb_ * SS + t) * UU + rj_] = hnew; // cross-kernel only
        }
        grid_barrier(bar, bid, (unsigned)t);
    }
}

// ---------------- generic fp32 GEMM: C[M,N] = A[M,K]@B[K,N] + bias (64x128 tile) ----------------
__global__ __launch_bounds__(256) void k_gemm(const float* __restrict__ A,
                                              const float* __restrict__ Bm,
                                              const float* __restrict__ bias,
                                              float* __restrict__ C,
                                              int M, int N, int K) {
    __shared__ float As[16][68];
    __shared__ float Bs[16][132];
    const int rb = blockIdx.x * 64;
    const int cb = blockIdx.y * 128;
    const int tid = threadIdx.x;
    const int cg = tid & 31;
    const int rg = tid >> 5;
    float acc[8][4] = {{0.f}};

    const int arow = tid >> 2, akq = (tid & 3) * 4;
    const int bkk = tid >> 4, bc8 = (tid & 15) * 8;
    const bool nfull = (cb + 128 <= N);

    for (int k0 = 0; k0 < K; k0 += 16) {
        {
            float4 a4 = *(const float4*)(A + (size_t)(rb + arow) * K + k0 + akq);
            As[akq + 0][arow] = a4.x; As[akq + 1][arow] = a4.y;
            As[akq + 2][arow] = a4.z; As[akq + 3][arow] = a4.w;
        }
        {
            int col = cb + bc8;
            const float* bp = Bm + (size_t)(k0 + bkk) * N + col;
            if (nfull) {
                float4 x0 = *(const float4*)bp;
                float4 x1 = *(const float4*)(bp + 4);
                Bs[bkk][bc8 + 0] = x0.x; Bs[bkk][bc8 + 1] = x0.y; Bs[bkk][bc8 + 2] = x0.z; Bs[bkk][bc8 + 3] = x0.w;
                Bs[bkk][bc8 + 4] = x1.x; Bs[bkk][bc8 + 5] = x1.y; Bs[bkk][bc8 + 6] = x1.z; Bs[bkk][bc8 + 7] = x1.w;
            } else {
                #pragma unroll
                for (int jj = 0; jj < 8; ++jj)
                    Bs[bkk][bc8 + jj] = (col + jj < N) ? bp[jj] : 0.0f;
            }
        }
        __syncthreads();
        #pragma unroll
        for (int kk = 0; kk < 16; ++kk) {
            float4 a0 = *(const float4*)&As[kk][rg * 8];
            float4 a1 = *(const float4*)&As[kk][rg * 8 + 4];
            float4 b0 = *(const float4*)&Bs[kk][cg * 4];
            float av[8] = {a0.x, a0.y, a0.z, a0.w, a1.x, a1.y, a1.z, a1.w};
            float bv[4] = {b0.x, b0.y, b0.z, b0.w};
            #pragma unroll
            for (int i = 0; i < 8; ++i)
                #pragma unroll
                for (int jj = 0; jj < 4; ++jj)
                    acc[i][jj] += av[i] * bv[jj];
        }
        __syncthreads();
    }
    const int col0 = cb + cg * 4;
    const bool cfull = (col0 + 4 <= N);
    #pragma unroll
    for (int i = 0; i < 8; ++i) {
        int row = rb + rg * 8 + i;
        float* cp = C + (size_t)row * N + col0;
        if (cfull) {
            float4 o;
            o.x = acc[i][0] + bias[col0 + 0];
            o.y = acc[i][1] + bias[col0 + 1];
            o.z = acc[i][2] + bias[col0 + 2];
            o.w = acc[i][3] + bias[col0 + 3];
            *(float4*)cp = o;
        } else {
            #pragma unroll
            for (int jj = 0; jj < 4; ++jj)
                if (col0 + jj < N) cp[jj] = acc[i][jj] + bias[col0 + jj];
        }
    }
}

// ---------------- 128x128-tile GEMM, 8x8 per thread (logits) ----------------
__global__ __launch_bounds__(256) void k_gemm128(const float* __restrict__ A,
                                                 const float* __restrict__ Bm,
                                                 const float* __restrict__ bias,
                                                 float* __restrict__ C,
                                                 int M, int N, int K) {
    __shared__ float As[16][132];
    __shared__ float Bs[16][132];
    const int rb = blockIdx.x * 128;
    const int cb = blockIdx.y * 128;
    const int tid = threadIdx.x;
    const int rg = tid >> 4;      // 0..15
    const int cg = tid & 15;      // 0..15
    float acc[8][8] = {{0.f}};

    const int arow = tid >> 1, akq = (tid & 1) * 8;
    const int bkk = tid >> 4, bc8 = (tid & 15) * 8;
    const bool nfull = (cb + 128 <= N);

    for (int k0 = 0; k0 < K; k0 += 16) {
        {
            const float* ap = A + (size_t)(rb + arow) * K + k0 + akq;
            float4 a0 = *(const float4*)ap;
            float4 a1 = *(const float4*)(ap + 4);
            As[akq + 0][arow] = a0.x; As[akq + 1][arow] = a0.y;
            As[akq + 2][arow] = a0.z; As[akq + 3][arow] = a0.w;
            As[akq + 4][arow] = a1.x; As[akq + 5][arow] = a1.y;
            As[akq + 6][arow] = a1.z; As[akq + 7][arow] = a1.w;
        }
        {
            int col = cb + bc8;
            const float* bp = Bm + (size_t)(k0 + bkk) * N + col;
            if (nfull) {
                *(float4*)&Bs[bkk][bc8] = *(const float4*)bp;
                *(float4*)&Bs[bkk][bc8 + 4] = *(const float4*)(bp + 4);
            } else {
                #pragma unroll
                for (int jj = 0; jj < 8; ++jj)
                    Bs[bkk][bc8 + jj] = (col + jj < N) ? bp[jj] : 0.0f;
            }
        }
        __syncthreads();
        #pragma unroll
        for (int kk = 0; kk < 16; ++kk) {
            float4 a0 = *(const float4*)&As[kk][rg * 8];
            float4 a1 = *(const float4*)&As[kk][rg * 8 + 4];
            float4 b0 = *(const float4*)&Bs[kk][cg * 8];
            float4 b1 = *(const float4*)&Bs[kk][cg * 8 + 4];
            float av[8] = {a0.x, a0.y, a0.z, a0.w, a1.x, a1.y, a1.z, a1.w};
            float bw[8] = {b0.x, b0.y, b0.z, b0.w, b1.x, b1.y, b1.z, b1.w};
            #pragma unroll
            for (int i = 0; i < 8; ++i)
                #pragma unroll
                for (int jj = 0; jj < 8; ++jj)
                    acc[i][jj] += av[i] * bw[jj];
        }
        __syncthreads();
    }
    const int col0 = cb + cg * 8;
    const bool cfull = (col0 + 8 <= N);
    #pragma unroll
    for (int i = 0; i < 8; ++i) {
        int row = rb + rg * 8 + i;
        float* cp = C + (size_t)row * N + col0;
        if (cfull) {
            float4 o0, o1;
            o0.x = acc[i][0] + bias[col0 + 0];
            o0.y = acc[i][1] + bias[col0 + 1];
            o0.z = acc[i][2] + bias[col0 + 2];
            o0.w = acc[i][3] + bias[col0 + 3];
            o1.x = acc[i][4] + bias[col0 + 4];
            o1.y = acc[i][5] + bias[col0 + 5];
            o1.z = acc[i][6] + bias[col0 + 6];
            o1.w = acc[i][7] + bias[col0 + 7];
            *(float4*)cp = o0;
            *(float4*)(cp + 4) = o1;
        } else {
            #pragma unroll
            for (int jj = 0; jj < 8; ++jj)
                if (col0 + jj < N) cp[jj] = acc[i][jj] + bias[col0 + jj];
        }
    }
}

// ---------------- decoder: 16 steps x 4 phases, persistent, 512 threads ----------------
// Fence-free: cross-block arrays (hT/hdT, q, esc, xT) via LLC-bypass loads;
// read-only arrays (pre, enc, GXd, Va, weights) stay L2-hot across all steps.
__global__ __launch_bounds__(512, 2) void k_decoder(const float* __restrict__ W2,
                                                    const float* __restrict__ b2,
                                                    const float* __restrict__ Va,
                                                    const float* __restrict__ bv,
                                                    const float* __restrict__ Wxd,
                                                    const float* __restrict__ b_rec,
                                                    float* __restrict__ ws) {
    float* hT = ws + WS_HT;            // slot 0 = encoder final hidden
    float* enc = ws + WS_ENC;
    float* pre = ws + WS_PRE;
    float* q = ws + WS_Q;
    float* esc = ws + WS_ESC;
    float* xT = ws + WS_XT;
    float* hdT = ws + WS_HDT;
    float* Hd = ws + WS_HD;
    float* GXd = ws + WS_GXD;
    unsigned* bar = (unsigned*)(ws + WS_BAR) + 1024;

    __shared__ float Wxds[12288];      // [k][12] g-major
    __shared__ float W2s[4096];        // [k][4] cols bid*4..+3
    __shared__ float scr[3072];        // cross-wave reduce scratch
    __shared__ float eL[64];
    __shared__ float attnL[64];
    __shared__ float shs[512];

    const int tid = threadIdx.x;
    const int bid = blockIdx.x;
    const int wv = tid >> 6;           // 0..7
    const int lane = tid & 63;
    const int kp = lane & 7;
    const int rg = lane >> 3;

    for (int k = tid; k < 1024; k += 512) {
        #pragma unroll
        for (int g = 0; g < 3; ++g)
            *(float4*)(Wxds + k * 12 + g * 4) =
                *(const float4*)(Wxd + (size_t)k * G3 + g * 1024 + bid * 4);
        *(float4*)(W2s + k * 4) = *(const float4*)(W2 + (size_t)k * UU + bid * 4);
    }

    float bzr_s = 0.f, brr_s = 0.f, bcr_s = 0.f, b2s = 0.f;
    int rc_ = 0, rb_ = 0, rj_ = 0;
    if (tid < 128) {
        rc_ = tid >> 5; rb_ = tid & 31; rj_ = bid * 4 + rc_;
        bzr_s = b_rec[rj_];
        brr_s = b_rec[1024 + rj_];
        bcr_s = b_rec[2048 + rj_];
        b2s = b2[rj_];
    }
    __syncthreads();

    const int hk0 = wv * 128 + kp;     // k-base for S1/S4 (16 k per lane)
    unsigned bc = 0;

    for (int t = 0; t < TT; ++t) {
        const float* hsrc = (t == 0) ? hT : hdT;

        // prefetch this step's GXd gate values (L2-resident, overlaps S1..S3)
        float gxz = 0.f, gxr = 0.f, gxc = 0.f;
        if (tid < 128) {
            const float* gx = GXd + (size_t)(t * BB + rb_) * G3;
            gxz = gx[rj_];
            gxr = gx[1024 + rj_];
            gxc = gx[2048 + rj_];
        }

        // ---- S1: q = dec_h @ W2 + b2 (encoder-shaped k-split, no redundancy) ----
        {
            f4v hb[16];
            llc_load16(hsrc + hk0 * 32 + rg * 4, hb);
            float4 aq[4];
            #pragma unroll
            for (int c = 0; c < 4; ++c) aq[c] = make_float4(0.f, 0.f, 0.f, 0.f);
            #pragma unroll
            for (int u = 0; u < 16; ++u) {
                f4v w4 = *(const f4v*)(W2s + (hk0 + 8 * u) * 4);
                f4v hv = hb[u];
                ACC4(aq[0], hv, w4.x); ACC4(aq[1], hv, w4.y);
                ACC4(aq[2], hv, w4.z); ACC4(aq[3], hv, w4.w);
            }
            #pragma unroll
            for (int m = 1; m <= 4; m <<= 1) {
                #pragma unroll
                for (int c = 0; c < 4; ++c) RED4(aq[c], m);
            }
            if (kp == 0) {
                float* sb = scr + wv * 128 + rg * 4;
                #pragma unroll
                for (int c = 0; c < 4; ++c) *(float4*)(sb + c * 32) = aq[c];
            }
            __syncthreads();
            if (tid < 128) {
                float s = 0.f;
                #pragma unroll
                for (int w = 0; w < 8; ++w) s += scr[w * 128 + rc_ * 32 + rb_];
                store_agent(&q[(size_t)rb_ * UU + rj_], s + b2s);
            }
        }
        grid_barrier(bar, bid, bc++);

        // ---- S2: scores e[b][s] = tanh(pre_enc + q) . Va + bv ----
        {
            const int b = bid >> 3, s0 = (bid & 7) * 8;
            const int pi = tid >> 6;           // wave id = source row
            const int kq = lane;               // 64-way k-split
            const int srow = s0 + pi;
            const float* pe = pre + ((size_t)b * SS + srow) * UU + kq * 16;
            const float* va = Va + kq * 16;
            f4v q4[4];
            llc_load4(q + (size_t)b * UU + kq * 16, q4);
            float acc = 0;
            #pragma unroll
            for (int kk = 0; kk < 4; ++kk) {
                float4 p4 = *(const float4*)(pe + kk * 4);
                float4 v4 = *(const float4*)(va + kk * 4);
                f4v qq = q4[kk];
                acc += tanhf(p4.x + qq.x) * v4.x + tanhf(p4.y + qq.y) * v4.y +
                       tanhf(p4.z + qq.z) * v4.z + tanhf(p4.w + qq.w) * v4.w;
            }
            #pragma unroll
            for (int m = 1; m <= 32; m <<= 1) acc += __shfl_xor(acc, m, 64);
            if (kq == 0) store_agent(&esc[b * SS + srow], acc + bv[0]);
        }
        grid_barrier(bar, bid, bc++);

        // ---- S3: softmax + ctx (enc L2-hot) into xT ----
        {
            const int b = bid >> 3, ug = bid & 7;
            if (tid < 64) eL[tid] = llc_loadf(&esc[b * SS + tid]);
            __syncthreads();
            if (tid < 64) {
                float v = eL[tid];
                float m = v;
                #pragma unroll
                for (int mm = 32; mm >= 1; mm >>= 1) m = fmaxf(m, __shfl_xor(m, mm, 64));
                float p = expf(v - m);
                float sum = p;
                #pragma unroll
                for (int mm = 32; mm >= 1; mm >>= 1) sum += __shfl_xor(sum, mm, 64);
                attnL[tid] = p / sum;
            }
            __syncthreads();
            const int u = ug * 128 + (tid & 127), sp = tid >> 7;   // sp 0..3
            float acc = 0;
            #pragma unroll 8
            for (int i = 0; i < 16; ++i) {
                int srow = sp * 16 + i;
                acc += attnL[srow] * enc[((size_t)b * SS + srow) * UU + u];
            }
            shs[(tid & 127) * 4 + sp] = acc;
            __syncthreads();
            if (tid < 128)
                store_agent(&xT[(size_t)(ug * 128 + tid) * BB + b],
                            shs[tid * 4] + shs[tid * 4 + 1] + shs[tid * 4 + 2] + shs[tid * 4 + 3]);
        }
        grid_barrier(bar, bid, bc++);

        // ---- S4: gx = ctx @ Wxd_top (+ GXd), k-split across 8 waves ----
        {
            float4 sz[4], sr_[4], sc_[4];
            #pragma unroll
            for (int c = 0; c < 4; ++c) {
                sz[c] = make_float4(0.f, 0.f, 0.f, 0.f);
                sr_[c] = make_float4(0.f, 0.f, 0.f, 0.f);
                sc_[c] = make_float4(0.f, 0.f, 0.f, 0.f);
            }
            f4v xb[16];
            llc_load16(xT + hk0 * 32 + rg * 4, xb);
            #pragma unroll
            for (int u = 0; u < 16; ++u) {
                const float* wp = Wxds + (hk0 + 8 * u) * 12;
                float4 wz = *(const float4*)wp;
                float4 wr4 = *(const float4*)(wp + 4);
                float4 wc4 = *(const float4*)(wp + 8);
                f4v xv = xb[u];
                ACC4(sz[0], xv, wz.x); ACC4(sz[1], xv, wz.y); ACC4(sz[2], xv, wz.z); ACC4(sz[3], xv, wz.w);
                ACC4(sr_[0], xv, wr4.x); ACC4(sr_[1], xv, wr4.y); ACC4(sr_[2], xv, wr4.z); ACC4(sr_[3], xv, wr4.w);
                ACC4(sc_[0], xv, wc4.x); ACC4(sc_[1], xv, wc4.y); ACC4(sc_[2], xv, wc4.z); ACC4(sc_[3], xv, wc4.w);
            }
            #pragma unroll
            for (int m = 1; m <= 4; m <<= 1) {
                #pragma unroll
                for (int c = 0; c < 4; ++c) { RED4(sz[c], m); RED4(sr_[c], m); RED4(sc_[c], m); }
            }
            if (kp == 0) {
                float* sb = scr + wv * 384 + rg * 4;
                #pragma unroll
                for (int c = 0; c < 4; ++c) {
                    *(float4*)(sb + c * 32) = sz[c];
                    *(float4*)(sb + 128 + c * 32) = sr_[c];
                    *(float4*)(sb + 256 + c * 32) = sc_[c];
                }
            }
            __syncthreads();
            if (tid < 128) {
                float ssz = 0.f, ssr = 0.f, ssc = 0.f;
                #pragma unroll
                for (int w = 0; w < 8; ++w) {
                    const float* sb = scr + w * 384 + rc_ * 32 + rb_;
                    ssz += sb[0]; ssr += sb[128]; ssc += sb[256];
                }
                float z = sigmoidf_(ssz + gxz + bzr_s);
                float rr = sigmoidf_(ssr + gxr + brr_s);
                float cc = tanhf(ssc + gxc + rr * bcr_s);
                float h = (1.0f - z) * cc;       // z*h0 + (1-z)*c, h0 = 0
                Hd[((size_t)rb_ * TT + t) * UU + rj_] = h;   // cross-kernel: normal
                store_agent(&hdT[(size_t)rj_ * BB + rb_], h);
            }
        }
        grid_barrier(bar, bid, bc++);
    }
}

// ---------------- argmax with numpy first-index tie-break ----------------
__global__ __launch_bounds__(256) void k_argmax(const float* __restrict__ logits,
                                                float* __restrict__ outp) {
    const int row = blockIdx.x;
    const float* lr = logits + (size_t)row * VV;
    const int tid = threadIdx.x;
    float best = -INFINITY;
    int bidx = 0x7fffffff;
    for (int c = tid; c < VV; c += 256) {
        float v = lr[c];
        if (v > best) { best = v; bidx = c; }
    }
    __shared__ float bv_[256];
    __shared__ int bi_[256];
    bv_[tid] = best; bi_[tid] = bidx;
    __syncthreads();
    for (int s2 = 128; s2 > 0; s2 >>= 1) {
        if (tid < s2) {
            float ov = bv_[tid + s2]; int oi = bi_[tid + s2];
            if (ov > bv_[tid] || (ov == bv_[tid] && oi < bi_[tid])) {
                bv_[tid] = ov; bi_[tid] = oi;
            }
        }
        __syncthreads();
    }
    if (tid == 0) outp[row] = (float)bi_[0];
}

extern "C" void kernel_launch(void* const* d_in, const int* in_sizes, int n_in,
                              void* d_out, int out_size, void* d_ws, size_t ws_size,
                              hipStream_t stream) {
    const int* enc_in = (const int*)d_in[0];
    const int* teacher = (const int*)d_in[1];
    const float* Ee = (const float*)d_in[4];
    const float* eWx = (const float*)d_in[5];
    const float* eWh = (const float*)d_in[6];
    const float* eb_in = (const float*)d_in[7];
    const float* eb_rec = (const float*)d_in[8];
    const float* Ed = (const float*)d_in[9];
    const float* dWx = (const float*)d_in[10];
    // d_in[11] dec_Wh structurally unused: h0_dec == 0 -> gh == b_rec
    const float* db_in = (const float*)d_in[12];
    const float* db_rec = (const float*)d_in[13];
    const float* W1 = (const float*)d_in[14];
    const float* b1 = (const float*)d_in[15];
    const float* W2 = (const float*)d_in[16];
    const float* b2 = (const float*)d_in[17];
    const float* Va = (const float*)d_in[18];
    const float* bvv = (const float*)d_in[19];
    const float* Wf = (const float*)d_in[20];
    const float* bf = (const float*)d_in[21];
    float* ws = (float*)d_ws;
    float* out = (float*)d_out;

    // prep: XembT gather + hT slot0 zero + Demb gather + barrier zero
    const int NTOT = SS * EE * BB + UU * BB + BB * TT * EE + 3072;
    k_prep<<<dim3((NTOT + 255) / 256), dim3(256), 0, stream>>>(enc_in, Ee, teacher, Ed, ws);

    // GXd = Demb @ dec_Wx[1024:1280,:] + dec_b_in : [512,256]x[256,3072]
    k_gemm<<<dim3(8, 24), dim3(256), 0, stream>>>(ws + WS_DEMB, dWx + (size_t)UU * G3, db_in,
                                                  ws + WS_GXD, BB * TT, G3, EE);

    // encoder recurrence (persistent, 64 steps, 512 threads/block)
    k_encoder<<<dim3(NBLK), dim3(512), 0, stream>>>(eWh, eWx, eb_in, eb_rec, ws);

    // pre_enc = encoded @ W1 + b1 : [2048,1024]x[1024,1024]
    k_gemm<<<dim3(32, 8), dim3(256), 0, stream>>>(ws + WS_ENC, W1, b1, ws + WS_PRE, BB * SS, UU, UU);

    // decoder (persistent, 16 steps x 4 phases, 512 threads/block)
    k_decoder<<<dim3(NBLK), dim3(512), 0, stream>>>(W2, b2, Va, bvv, dWx, db_rec, ws);

    // logits = Hdec @ Wf + bf : [512,1024]x[1024,20200] -> d_out (128x128 tile)
    k_gemm128<<<dim3(4, 158), dim3(256), 0, stream>>>(ws + WS_HD, Wf, bf, out, BB * TT, VV, UU);

    // predictions = argmax(logits)
    k_argmax<<<dim3(BB * TT), dim3(256), 0, stream>>>(out, out + (size_t)BB * TT * VV);
}